// Round 1
// baseline (338.997 us; speedup 1.0000x reference)
//
#include <hip/hip_runtime.h>
#include <stdint.h>

#define B_SZ 8192
#define D_SZ 1024
#define H_SZ 4096
#define O_SZ 1000

typedef float f32x4 __attribute__((ext_vector_type(4)));
typedef __bf16 bf16x8 __attribute__((ext_vector_type(8)));

// ---------------- fp32 -> bf16 (round-to-nearest-even) ----------------
static __device__ __forceinline__ uint16_t f2bf(float f) {
  uint32_t u = __float_as_uint(f);
  uint32_t r = (u + 0x7fffu + ((u >> 16) & 1u)) >> 16;
  return (uint16_t)r;
}

__global__ __launch_bounds__(256) void convert_bf16(const float* __restrict__ src,
                                                    ushort4* __restrict__ dst, int n4) {
  int i = blockIdx.x * blockDim.x + threadIdx.x;
  if (i < n4) {
    f32x4 v = reinterpret_cast<const f32x4*>(src)[i];
    ushort4 o;
    o.x = f2bf(v[0]); o.y = f2bf(v[1]); o.z = f2bf(v[2]); o.w = f2bf(v[3]);
    dst[i] = o;
  }
}

// ---------------- w2 in f64 (exact score needs it) ----------------
__global__ __launch_bounds__(64) void w2_kernel(const float* __restrict__ w,
                                                double* __restrict__ w2d) {
  const int h = blockIdx.x;
  const int l = threadIdx.x;
  const f32x4* wr = reinterpret_cast<const f32x4*>(w + (size_t)h * D_SZ);
  double s = 0.0;
#pragma unroll
  for (int j = 0; j < 4; ++j) {
    f32x4 v = wr[j * 64 + l];
    s += (double)v[0] * v[0] + (double)v[1] * v[1] + (double)v[2] * v[2] + (double)v[3] * v[3];
  }
#pragma unroll
  for (int m = 32; m; m >>= 1) s += __shfl_xor(s, m);
  if (l == 0) w2d[h] = s;
}

// ---------------- phase 1: bf16 MFMA GEMM -> per-(row, 32h-subtile) max ----------------
// tile 128x128, 4 waves (2x2), each wave 64x64 = 4x4 frags of 16x16x32. K-step 64.
// LDS pitch: 64 data bf16 + 8 pad = 72 bf16 = 144 B (16B aligned; conflict-free b128 r/w).
#define LPITCH 72
__global__ __launch_bounds__(256) void kohonen_gemm(const uint16_t* __restrict__ xb,
                                                    const uint16_t* __restrict__ wb,
                                                    float* __restrict__ tilemax) {
  __shared__ uint16_t As[128 * LPITCH];
  __shared__ uint16_t Bs[128 * LPITCH];
  const int tid = threadIdx.x;
  const int bm = blockIdx.x, bn = blockIdx.y;
  const int lane = tid & 63, wv = tid >> 6;
  const int wm = wv >> 1, wn = wv & 1;
  f32x4 acc[4][4] = {};

  const int sr = tid >> 3;  // staging row base (0..31)
  const int sp = tid & 7;   // 16B part within a 128B row
  const uint16_t* xrow = xb + (size_t)(bm * 128) * D_SZ;
  const uint16_t* wrow = wb + (size_t)(bn * 128) * D_SZ;

  for (int kt = 0; kt < D_SZ / 64; ++kt) {
    __syncthreads();
#pragma unroll
    for (int i = 0; i < 4; ++i) {
      const int r = sr + i * 32;
      const int4 va = *reinterpret_cast<const int4*>(xrow + (size_t)r * D_SZ + kt * 64 + sp * 8);
      *reinterpret_cast<int4*>(&As[r * LPITCH + sp * 8]) = va;
      const int4 vb = *reinterpret_cast<const int4*>(wrow + (size_t)r * D_SZ + kt * 64 + sp * 8);
      *reinterpret_cast<int4*>(&Bs[r * LPITCH + sp * 8]) = vb;
    }
    __syncthreads();
#pragma unroll
    for (int s = 0; s < 2; ++s) {
      bf16x8 a[4], b[4];
      const int col = s * 32 + (lane >> 4) * 8;
#pragma unroll
      for (int f = 0; f < 4; ++f) {
        a[f] = *reinterpret_cast<const bf16x8*>(&As[(wm * 64 + f * 16 + (lane & 15)) * LPITCH + col]);
        b[f] = *reinterpret_cast<const bf16x8*>(&Bs[(wn * 64 + f * 16 + (lane & 15)) * LPITCH + col]);
      }
#pragma unroll
      for (int fm = 0; fm < 4; ++fm)
#pragma unroll
        for (int fn = 0; fn < 4; ++fn)
          acc[fm][fn] = __builtin_amdgcn_mfma_f32_16x16x32_bf16(a[fm], b[fn], acc[fm][fn], 0, 0, 0);
    }
  }

  // epilogue: per row, max over each 32-wide h subtile.
  // C/D layout (m89-verified): col = lane&15, row = (lane>>4)*4 + j.
#pragma unroll
  for (int fm = 0; fm < 4; ++fm) {
#pragma unroll
    for (int s = 0; s < 2; ++s) {
      float v[4];
#pragma unroll
      for (int j = 0; j < 4; ++j) v[j] = fmaxf(acc[fm][2 * s][j], acc[fm][2 * s + 1][j]);
#pragma unroll
      for (int m = 1; m < 16; m <<= 1) {
#pragma unroll
        for (int j = 0; j < 4; ++j) v[j] = fmaxf(v[j], __shfl_xor(v[j], m));
      }
      if ((lane & 15) == 0) {
        const int g = lane >> 4;
        const int tile = bn * 4 + wn * 2 + s;
#pragma unroll
        for (int j = 0; j < 4; ++j) {
          const int row = bm * 128 + wm * 64 + fm * 16 + g * 4 + j;
          tilemax[(size_t)row * 128 + tile] = v[j];
        }
      }
    }
  }
}

// ---------------- phase 2: exact f64 rescore of candidate subtiles ----------------
#define MARGIN 0.08f
__global__ __launch_bounds__(256) void rescore_argmin(const float* __restrict__ x,
                                                      const float* __restrict__ w,
                                                      const double* __restrict__ w2d,
                                                      const float* __restrict__ tilemax,
                                                      int* __restrict__ winners,
                                                      float* __restrict__ winners_f) {
  const int row = blockIdx.x;
  const int tid = threadIdx.x;
  const int lane = tid & 63, wv = tid >> 6;
  __shared__ float xs[D_SZ];
  __shared__ float Msh;
  __shared__ int list[128];
  __shared__ int cnt;
  __shared__ double bSs[4];
  __shared__ int bIs[4];

  reinterpret_cast<f32x4*>(xs)[tid] = reinterpret_cast<const f32x4*>(x + (size_t)row * D_SZ)[tid];
  if (tid == 0) cnt = 0;
  __syncthreads();
  if (tid == 0) {
    float m = -1e30f;
    const float* tm = tilemax + (size_t)row * 128;
    for (int i = 0; i < 128; ++i) m = fmaxf(m, tm[i]);
    Msh = m;
  }
  __syncthreads();
  if (tid < 128) {
    if (tilemax[(size_t)row * 128 + tid] >= Msh - MARGIN) {
      int p = atomicAdd(&cnt, 1);
      list[p] = tid;
    }
  }
  __syncthreads();
  const int n = cnt;  // >= 1 always
  double bestS = -1e300;
  int bestI = 0x7fffffff;
  for (int ci = wv; ci < n; ci += 4) {
    const int tile = list[ci];
    for (int hh = 0; hh < 32; ++hh) {
      const int h = tile * 32 + hh;
      const f32x4* wr = reinterpret_cast<const f32x4*>(w + (size_t)h * D_SZ);
      const f32x4* xr = reinterpret_cast<const f32x4*>(xs);
      double dot = 0.0;
#pragma unroll
      for (int j = 0; j < 4; ++j) {
        f32x4 wvv = wr[j * 64 + lane];
        f32x4 xvv = xr[j * 64 + lane];
        dot += (double)xvv[0] * wvv[0] + (double)xvv[1] * wvv[1] +
               (double)xvv[2] * wvv[2] + (double)xvv[3] * wvv[3];
      }
#pragma unroll
      for (int m = 32; m; m >>= 1) dot += __shfl_xor(dot, m);
      const double sc = 2.0 * dot - w2d[h];  // maximize  <=>  minimize d2
      if (sc > bestS || (sc == bestS && h < bestI)) { bestS = sc; bestI = h; }
    }
  }
  if (lane == 0) { bSs[wv] = bestS; bIs[wv] = bestI; }
  __syncthreads();
  if (tid == 0) {
    double S = bSs[0];
    int I = bIs[0];
    for (int k = 1; k < 4; ++k)
      if (bSs[k] > S || (bSs[k] == S && bIs[k] < I)) { S = bSs[k]; I = bIs[k]; }
    winners[row] = I;
    winners_f[row] = (float)I;
  }
}

// ---------------- phase 3a: transpose grossberg [O][H] -> GT [H][O] ----------------
__global__ __launch_bounds__(256) void transpose_g(const float* __restrict__ g,
                                                   float* __restrict__ gt) {
  __shared__ float t[32][33];
  const int h0 = blockIdx.x * 32;
  const int o0 = blockIdx.y * 32;
  const int lx = threadIdx.x & 31, ly = threadIdx.x >> 5;
  for (int i = ly; i < 32; i += 8) {
    const int o = o0 + i;
    t[i][lx] = (o < O_SZ) ? g[(size_t)o * H_SZ + (h0 + lx)] : 0.f;
  }
  __syncthreads();
  for (int i = ly; i < 32; i += 8) {
    const int o = o0 + lx;
    if (o < O_SZ) gt[(size_t)(h0 + i) * O_SZ + o] = t[lx][i];
  }
}

// ---------------- phase 3b: row gather + scalar ----------------
__global__ __launch_bounds__(256) void gather_out(const float* __restrict__ gt,
                                                  const int* __restrict__ winners,
                                                  float* __restrict__ out) {
  const int row = blockIdx.x;
  const int wsel = winners[row];
  const f32x4* src = reinterpret_cast<const f32x4*>(gt + (size_t)wsel * O_SZ);
  f32x4* dst = reinterpret_cast<f32x4*>(out + (size_t)row * O_SZ);
  if (threadIdx.x < O_SZ / 4) dst[threadIdx.x] = src[threadIdx.x];
  if (row == 0 && threadIdx.x == 0)
    out[(size_t)B_SZ * O_SZ + B_SZ] = (float)B_SZ;  // scalar output: x.shape[0]
}

// ---------------- launch ----------------
extern "C" void kernel_launch(void* const* d_in, const int* in_sizes, int n_in,
                              void* d_out, int out_size, void* d_ws, size_t ws_size,
                              hipStream_t stream) {
  const float* x  = (const float*)d_in[0];
  const float* kw = (const float*)d_in[1];
  const float* gw = (const float*)d_in[2];
  float* out = (float*)d_out;
  char* ws = (char*)d_ws;

  // ws layout (bytes):
  //   xb      @ 0          : 8192*1024*2 = 16,777,216
  //   wb      @ 16,777,216 : 4096*1024*2 =  8,388,608
  //   tilemax @ 25,165,824 : 8192*128*4  =  4,194,304
  //   winners @ 29,360,128 : 8192*4      =     32,768
  //   w2d     @ 29,392,896 : 4096*8      =     32,768
  //   GT aliases xb (16,384,000 <= 16,777,216; xb is dead after phase 1)
  uint16_t* xb     = (uint16_t*)(ws);
  uint16_t* wb     = (uint16_t*)(ws + 16777216);
  float*    tmx    = (float*)   (ws + 25165824);
  int*      winers = (int*)     (ws + 29360128);
  double*   w2d    = (double*)  (ws + 29392896);
  float*    gt     = (float*)   (ws);  // alias of xb, used after phase 2

  convert_bf16<<<(B_SZ * D_SZ / 4 + 255) / 256, 256, 0, stream>>>(x, (ushort4*)xb, B_SZ * D_SZ / 4);
  convert_bf16<<<(H_SZ * D_SZ / 4 + 255) / 256, 256, 0, stream>>>(kw, (ushort4*)wb, H_SZ * D_SZ / 4);
  w2_kernel<<<H_SZ, 64, 0, stream>>>(kw, w2d);

  dim3 g1(B_SZ / 128, H_SZ / 128);
  kohonen_gemm<<<g1, 256, 0, stream>>>(xb, wb, tmx);

  rescore_argmin<<<B_SZ, 256, 0, stream>>>(x, kw, w2d, tmx, winers, out + (size_t)B_SZ * O_SZ);

  dim3 g3(H_SZ / 32, (O_SZ + 31) / 32);
  transpose_g<<<g3, 256, 0, stream>>>(gw, gt);

  gather_out<<<B_SZ, 256, 0, stream>>>(gt, winers, out);
}

// Round 2
// 139.082 us; speedup vs baseline: 2.4374x; 2.4374x over previous
//
#include <hip/hip_runtime.h>
#include <stdint.h>

#define B_SZ 8192
#define D_SZ 1024
#define H_SZ 4096
#define O_SZ 1000

#define MARGIN 0.0625f

typedef float f32x4 __attribute__((ext_vector_type(4)));
typedef __bf16 bf16x8 __attribute__((ext_vector_type(8)));

// ---------------- fp32 -> bf16 (round-to-nearest-even) ----------------
static __device__ __forceinline__ uint16_t f2bf(float f) {
  uint32_t u = __float_as_uint(f);
  uint32_t r = (u + 0x7fffu + ((u >> 16) & 1u)) >> 16;
  return (uint16_t)r;
}

__global__ __launch_bounds__(256) void convert_bf16(const float* __restrict__ src,
                                                    ushort4* __restrict__ dst, int n4) {
  int i = blockIdx.x * blockDim.x + threadIdx.x;
  if (i < n4) {
    f32x4 v = reinterpret_cast<const f32x4*>(src)[i];
    ushort4 o;
    o.x = f2bf(v[0]); o.y = f2bf(v[1]); o.z = f2bf(v[2]); o.w = f2bf(v[3]);
    dst[i] = o;
  }
}

// ---------------- w2 in f64 (exact score needs it) ----------------
__global__ __launch_bounds__(64) void w2_kernel(const float* __restrict__ w,
                                                double* __restrict__ w2d) {
  const int h = blockIdx.x;
  const int l = threadIdx.x;
  const f32x4* wr = reinterpret_cast<const f32x4*>(w + (size_t)h * D_SZ);
  double s = 0.0;
#pragma unroll
  for (int j = 0; j < 4; ++j) {
    f32x4 v = wr[j * 64 + l];
    s += (double)v[0] * v[0] + (double)v[1] * v[1] + (double)v[2] * v[2] + (double)v[3] * v[3];
  }
#pragma unroll
  for (int m = 32; m; m >>= 1) s += __shfl_xor(s, m);
  if (l == 0) w2d[h] = s;
}

// ---------------- phase 1: bf16 MFMA GEMM -> per-(row, 64h-tile) (max, candidate mask) ----------------
// tile 128x128, 4 waves (2x2), each wave 64x64 = 4x4 frags of 16x16x32. K-step 64.
// LDS pitch: 64 data bf16 + 8 pad = 72 bf16 = 144 B (16B aligned; conflict-free b128 r/w).
#define LPITCH 72
__global__ __launch_bounds__(256) void kohonen_gemm(const uint16_t* __restrict__ xb,
                                                    const uint16_t* __restrict__ wb,
                                                    float* __restrict__ tmax64,
                                                    unsigned long long* __restrict__ tmask64) {
  __shared__ uint16_t As[128 * LPITCH];
  __shared__ uint16_t Bs[128 * LPITCH];
  const int tid = threadIdx.x;
  const int bm = blockIdx.x, bn = blockIdx.y;
  const int lane = tid & 63, wv = tid >> 6;
  const int wm = wv >> 1, wn = wv & 1;
  f32x4 acc[4][4] = {};

  const int sr = tid >> 3;  // staging row base (0..31)
  const int sp = tid & 7;   // 16B part within a 128B row
  const uint16_t* xrow = xb + (size_t)(bm * 128) * D_SZ;
  const uint16_t* wrow = wb + (size_t)(bn * 128) * D_SZ;

  for (int kt = 0; kt < D_SZ / 64; ++kt) {
    __syncthreads();
#pragma unroll
    for (int i = 0; i < 4; ++i) {
      const int r = sr + i * 32;
      const int4 va = *reinterpret_cast<const int4*>(xrow + (size_t)r * D_SZ + kt * 64 + sp * 8);
      *reinterpret_cast<int4*>(&As[r * LPITCH + sp * 8]) = va;
      const int4 vb = *reinterpret_cast<const int4*>(wrow + (size_t)r * D_SZ + kt * 64 + sp * 8);
      *reinterpret_cast<int4*>(&Bs[r * LPITCH + sp * 8]) = vb;
    }
    __syncthreads();
#pragma unroll
    for (int s = 0; s < 2; ++s) {
      bf16x8 a[4], b[4];
      const int col = s * 32 + (lane >> 4) * 8;
#pragma unroll
      for (int f = 0; f < 4; ++f) {
        a[f] = *reinterpret_cast<const bf16x8*>(&As[(wm * 64 + f * 16 + (lane & 15)) * LPITCH + col]);
        b[f] = *reinterpret_cast<const bf16x8*>(&Bs[(wn * 64 + f * 16 + (lane & 15)) * LPITCH + col]);
      }
#pragma unroll
      for (int fm = 0; fm < 4; ++fm)
#pragma unroll
        for (int fn = 0; fn < 4; ++fn)
          acc[fm][fn] = __builtin_amdgcn_mfma_f32_16x16x32_bf16(a[fm], b[fn], acc[fm][fn], 0, 0, 0);
    }
  }

  // epilogue: per row, (max, within-margin bitmask) over this wave's 64 h.
  // C/D layout (m89-verified): col(h) = lane&15, row = (lane>>4)*4 + j.
  // Wave wn owns h-tile (bn*2 + wn), 64 wide; bit position = fn*16 + (lane&15).
  const int tile = bn * 2 + wn;
  const int colid = lane & 15;
  const int g = lane >> 4;
#pragma unroll
  for (int fm = 0; fm < 4; ++fm) {
    float v[4];
#pragma unroll
    for (int j = 0; j < 4; ++j)
      v[j] = fmaxf(fmaxf(acc[fm][0][j], acc[fm][1][j]), fmaxf(acc[fm][2][j], acc[fm][3][j]));
#pragma unroll
    for (int m = 1; m < 16; m <<= 1) {
#pragma unroll
      for (int j = 0; j < 4; ++j) v[j] = fmaxf(v[j], __shfl_xor(v[j], m));
    }
    unsigned long long mk[4];
#pragma unroll
    for (int j = 0; j < 4; ++j) {
      unsigned long long b = 0;
      const float thr = v[j] - MARGIN;
#pragma unroll
      for (int fn = 0; fn < 4; ++fn)
        if (acc[fm][fn][j] >= thr) b |= 1ull << (fn * 16 + colid);
      mk[j] = b;
    }
#pragma unroll
    for (int m = 1; m < 16; m <<= 1) {
#pragma unroll
      for (int j = 0; j < 4; ++j) mk[j] |= __shfl_xor(mk[j], m);
    }
    if (colid == 0) {
#pragma unroll
      for (int j = 0; j < 4; ++j) {
        const int row = bm * 128 + wm * 64 + fm * 16 + g * 4 + j;
        tmax64[(size_t)row * 64 + tile] = v[j];
        tmask64[(size_t)row * 64 + tile] = mk[j];
      }
    }
  }
}

// ---------------- phase 2: exact f64 rescore of candidate h's (one wave per row) ----------------
__global__ __launch_bounds__(64) void rescore2(const float* __restrict__ x,
                                               const float* __restrict__ w,
                                               const double* __restrict__ w2d,
                                               const float* __restrict__ tmax64,
                                               const unsigned long long* __restrict__ tmask64,
                                               int* __restrict__ winners,
                                               float* __restrict__ winners_f) {
  const int row = blockIdx.x;
  const int l = threadIdx.x;

  // x row, lane-sliced (coalesced): xr[j] = x[row*1024 + j*256 + l*4 .. +3]
  f32x4 xr[4];
  const f32x4* xp = reinterpret_cast<const f32x4*>(x + (size_t)row * D_SZ);
#pragma unroll
  for (int j = 0; j < 4; ++j) xr[j] = xp[j * 64 + l];

  // lane l owns 64h-tile l
  const float pmax = tmax64[(size_t)row * 64 + l];
  const unsigned long long pmask = tmask64[(size_t)row * 64 + l];
  float M = pmax;
#pragma unroll
  for (int m = 1; m < 64; m <<= 1) M = fmaxf(M, __shfl_xor(M, m));
  const float thr = M - MARGIN;

  double bestS = -1e300;
  int bestI = 0x7fffffff;

  unsigned long long bits = __ballot(pmax >= thr && pmask != 0ull);
  while (bits) {
    const int src = __ffsll(bits) - 1;
    unsigned long long tmask = __shfl(pmask, src);
    const int tile = src;
    while (tmask) {
      const int b = __ffsll(tmask) - 1;
      const int h = tile * 64 + b;
      const f32x4* wp = reinterpret_cast<const f32x4*>(w + (size_t)h * D_SZ);
      double dot = 0.0;
#pragma unroll
      for (int j = 0; j < 4; ++j) {
        f32x4 wv = wp[j * 64 + l];
        dot += (double)xr[j][0] * wv[0] + (double)xr[j][1] * wv[1] +
               (double)xr[j][2] * wv[2] + (double)xr[j][3] * wv[3];
      }
#pragma unroll
      for (int m = 32; m; m >>= 1) dot += __shfl_xor(dot, m);
      const double sc = 2.0 * dot - w2d[h];  // maximize  <=>  minimize d2
      if (sc > bestS || (sc == bestS && h < bestI)) { bestS = sc; bestI = h; }
      tmask &= tmask - 1;
    }
    bits &= bits - 1;
  }

  if (l == 0) { winners[row] = bestI; winners_f[row] = (float)bestI; }
}

// ---------------- phase 3a: transpose grossberg [O][H] -> GT [H][O] ----------------
__global__ __launch_bounds__(256) void transpose_g(const float* __restrict__ g,
                                                   float* __restrict__ gt) {
  __shared__ float t[32][33];
  const int h0 = blockIdx.x * 32;
  const int o0 = blockIdx.y * 32;
  const int lx = threadIdx.x & 31, ly = threadIdx.x >> 5;
  for (int i = ly; i < 32; i += 8) {
    const int o = o0 + i;
    t[i][lx] = (o < O_SZ) ? g[(size_t)o * H_SZ + (h0 + lx)] : 0.f;
  }
  __syncthreads();
  for (int i = ly; i < 32; i += 8) {
    const int o = o0 + lx;
    if (o < O_SZ) gt[(size_t)(h0 + i) * O_SZ + o] = t[lx][i];
  }
}

// ---------------- phase 3b: row gather + scalar ----------------
__global__ __launch_bounds__(256) void gather_out(const float* __restrict__ gt,
                                                  const int* __restrict__ winners,
                                                  float* __restrict__ out) {
  const int row = blockIdx.x;
  const int wsel = winners[row];
  const f32x4* src = reinterpret_cast<const f32x4*>(gt + (size_t)wsel * O_SZ);
  f32x4* dst = reinterpret_cast<f32x4*>(out + (size_t)row * O_SZ);
  if (threadIdx.x < O_SZ / 4) dst[threadIdx.x] = src[threadIdx.x];
  if (row == 0 && threadIdx.x == 0)
    out[(size_t)B_SZ * O_SZ + B_SZ] = (float)B_SZ;  // scalar output: x.shape[0]
}

// ---------------- launch ----------------
extern "C" void kernel_launch(void* const* d_in, const int* in_sizes, int n_in,
                              void* d_out, int out_size, void* d_ws, size_t ws_size,
                              hipStream_t stream) {
  const float* x  = (const float*)d_in[0];
  const float* kw = (const float*)d_in[1];
  const float* gw = (const float*)d_in[2];
  float* out = (float*)d_out;
  char* ws = (char*)d_ws;

  // ws layout (bytes):
  //   xb      @ 0          : 8192*1024*2 = 16,777,216
  //   wb      @ 16,777,216 : 4096*1024*2 =  8,388,608
  //   tmax64  @ 25,165,824 : 8192*64*4   =  2,097,152
  //   tmask64 @ 27,262,976 : 8192*64*8   =  4,194,304
  //   winners @ 31,457,280 : 8192*4      =     32,768
  //   w2d     @ 31,490,048 : 4096*8      =     32,768
  //   GT aliases xb (16,384,000 <= 16,777,216; xb is dead after phase 1)
  uint16_t*           xb   = (uint16_t*)(ws);
  uint16_t*           wb   = (uint16_t*)(ws + 16777216);
  float*              tmx  = (float*)   (ws + 25165824);
  unsigned long long* tmk  = (unsigned long long*)(ws + 27262976);
  int*                wins = (int*)     (ws + 31457280);
  double*             w2d  = (double*)  (ws + 31490048);
  float*              gt   = (float*)   (ws);  // alias of xb, used after phase 2

  convert_bf16<<<(B_SZ * D_SZ / 4 + 255) / 256, 256, 0, stream>>>(x, (ushort4*)xb, B_SZ * D_SZ / 4);
  convert_bf16<<<(H_SZ * D_SZ / 4 + 255) / 256, 256, 0, stream>>>(kw, (ushort4*)wb, H_SZ * D_SZ / 4);
  w2_kernel<<<H_SZ, 64, 0, stream>>>(kw, w2d);

  dim3 g1(B_SZ / 128, H_SZ / 128);
  kohonen_gemm<<<g1, 256, 0, stream>>>(xb, wb, tmx, tmk);

  rescore2<<<B_SZ, 64, 0, stream>>>(x, kw, w2d, tmx, tmk, wins, out + (size_t)B_SZ * O_SZ);

  dim3 g3(H_SZ / 32, (O_SZ + 31) / 32);
  transpose_g<<<g3, 256, 0, stream>>>(gw, gt);

  gather_out<<<B_SZ, 256, 0, stream>>>(gt, wins, out);
}